// Round 10
// baseline (316.888 us; speedup 1.0000x reference)
//
#include <hip/hip_runtime.h>
#include <math.h>

#define N_NODES 50000
#define N_EDGES 800000
#define N_ETOT  850000          // + self loops
#define C_IN    128
#define C_HID   96
#define C_OUT   40
#define NEG_SLOPE 0.2f
#define NSB ((N_NODES + 1023) / 1024)   // 49 scan blocks
#define NPART 8
#define PART_SZ ((N_NODES + NPART - 1) / NPART)   // 6250

// ---------------- bf16 helpers ----------------
__device__ __forceinline__ unsigned short f2bf(float f) {
    unsigned u = __float_as_uint(f);
    u = u + 0x7fffu + ((u >> 16) & 1u);     // round-to-nearest-even
    return (unsigned short)(u >> 16);
}
__device__ __forceinline__ float bfu_lo(unsigned g) { return __uint_as_float(g << 16); }
__device__ __forceinline__ float bfu_hi(unsigned g) { return __uint_as_float(g & 0xffff0000u); }

// ---------------- CSR build ----------------

__global__ void k_initdeg(int* __restrict__ deg) {
    int i = blockIdx.x * blockDim.x + threadIdx.x;
    if (i < N_NODES) deg[i] = 1;            // self loop
}

// dst-partitioned histogram: blocks with bid%NPART==p count only dst in partition p
__global__ void k_hist(const int* __restrict__ ei, int* __restrict__ deg) {
    int p  = blockIdx.x & (NPART - 1);
    int qb = blockIdx.x / NPART;
    int nq = gridDim.x / NPART;
    int lo = p * PART_SZ, hi = min(N_NODES, lo + PART_SZ);
    int stride = nq * blockDim.x;
    for (int i = qb * blockDim.x + threadIdx.x; i < N_EDGES; i += stride) {
        int d = ei[N_EDGES + i];
        if (d >= lo && d < hi) atomicAdd(&deg[d], 1);
    }
}

// hierarchical exclusive scan: per-block scan -> scan of block sums -> add offsets
__global__ void k_scan1(const int* __restrict__ deg, int* __restrict__ rp,
                        int* __restrict__ bsum) {
    __shared__ int wsum[16];
    int t = threadIdx.x, lane = t & 63, w = t >> 6;
    int i = blockIdx.x * 1024 + t;
    int v = (i < N_NODES) ? deg[i] : 0;
    int inc = v;
    #pragma unroll
    for (int off = 1; off < 64; off <<= 1) {
        int u = __shfl_up(inc, off);
        if (lane >= off) inc += u;
    }
    if (lane == 63) wsum[w] = inc;
    __syncthreads();
    if (w == 0) {
        int sv = (lane < 16) ? wsum[lane] : 0;
        #pragma unroll
        for (int off = 1; off < 16; off <<= 1) {
            int u = __shfl_up(sv, off);
            if (lane >= off) sv += u;
        }
        if (lane < 16) wsum[lane] = sv;       // inclusive over waves
    }
    __syncthreads();
    int exc = ((w == 0) ? 0 : wsum[w - 1]) + inc - v;
    if (i < N_NODES) rp[i] = exc;
    if (t == 0) bsum[blockIdx.x] = wsum[15];
}

__global__ void k_scan2(const int* __restrict__ bsum, int* __restrict__ boff,
                        int* __restrict__ rp) {
    int lane = threadIdx.x;   // 64 threads
    int v = (lane < NSB) ? bsum[lane] : 0;
    int inc = v;
    #pragma unroll
    for (int off = 1; off < 64; off <<= 1) {
        int u = __shfl_up(inc, off);
        if (lane >= off) inc += u;
    }
    if (lane < NSB) boff[lane] = inc - v;
    if (lane == 63) rp[N_NODES] = inc;        // total == N_ETOT
}

__global__ void k_scan3(int* __restrict__ rp, const int* __restrict__ boff,
                        int* __restrict__ cursor) {
    int i = blockIdx.x * blockDim.x + threadIdx.x;
    if (i < N_NODES) {
        int v = rp[i] + boff[i >> 10];
        rp[i] = v; cursor[i] = v;
    }
}

// dst-partitioned scatter (XCD-local cursor atomics + csr_src lines)
__global__ void k_scatter(const int* __restrict__ ei, int* __restrict__ cursor,
                          int* __restrict__ csr_src) {
    int p  = blockIdx.x & (NPART - 1);
    int qb = blockIdx.x / NPART;
    int nq = gridDim.x / NPART;
    int lo = p * PART_SZ, hi = min(N_NODES, lo + PART_SZ);
    int stride = nq * blockDim.x;
    for (int i = qb * blockDim.x + threadIdx.x; i < N_ETOT; i += stride) {
        int src, dst;
        if (i < N_EDGES) { src = ei[i]; dst = ei[N_EDGES + i]; }   // coalesced reads
        else             { src = dst = i - N_EDGES; }
        if (dst >= lo && dst < hi) {
            int pos = atomicAdd(&cursor[dst], 1);
            csr_src[pos] = src;
        }
    }
}

// ---------------- tiled GEMM + fused alpha dots, bf16 H output ----------------
// H[N, COUT](bf16) = X[N, CIN] @ W[CIN, COUT]; as[n]=H[n]·asrc; ad[n]=H[n]·adst (fp32)
// float4 LDS reads both sides; k unrolled by 4 (w0..w3); node-interleaved thread
// mapping (n = i*NT + nt) so per-step xs reads hit consecutive bank quads.

template<int CIN, int COUT, int KH, int CT, int NT, int NP>
__global__ __launch_bounds__(CT * NT)
void k_gemm(const float* __restrict__ X, const float* __restrict__ W,
            const float* __restrict__ asrc, const float* __restrict__ adst,
            unsigned short* __restrict__ Hb, float* __restrict__ as, float* __restrict__ ad) {
    constexpr int NPB = NT * NP;
    constexpr int BLK = CT * NT;
    constexpr int KQ  = CIN / 4;        // f4 per x row
    constexpr int XS  = KQ + 1;         // padded row stride (f4)
    constexpr int CQ  = COUT / 4;
    __shared__ float4 xs4[NPB][XS];
    __shared__ float4 Ws4[KH][CQ + 1];
    __shared__ float red[NPB * 2];
    const int t  = threadIdx.x;
    const int nb = blockIdx.x * NPB;

    for (int idx = t; idx < NPB * 2; idx += BLK) red[idx] = 0.f;

    for (int idx = t; idx < NPB * KQ; idx += BLK) {
        int n = idx / KQ, kq = idx - n * KQ;
        float4 v = make_float4(0.f, 0.f, 0.f, 0.f);
        if (nb + n < N_NODES)
            v = reinterpret_cast<const float4*>(X)[(size_t)(nb + n) * KQ + kq];
        xs4[n][kq] = v;
    }

    const int ct = t % CT, nt = t / CT;
    float acc[NP][4] = {};

    for (int kb = 0; kb < CIN; kb += KH) {
        __syncthreads();                    // xs ready / Ws reusable
        for (int idx = t; idx < KH * CQ; idx += BLK) {
            int kk = idx / CQ, c4 = idx - kk * CQ;
            Ws4[kk][c4] = reinterpret_cast<const float4*>(W)[(size_t)(kb + kk) * CQ + c4];
        }
        __syncthreads();
        const int kb4 = kb / 4;
        #pragma unroll 2
        for (int kq = 0; kq < KH / 4; ++kq) {
            float4 w0 = Ws4[4 * kq + 0][ct];
            float4 w1 = Ws4[4 * kq + 1][ct];
            float4 w2 = Ws4[4 * kq + 2][ct];
            float4 w3 = Ws4[4 * kq + 3][ct];
            #pragma unroll
            for (int i = 0; i < NP; ++i) {
                float4 xv = xs4[i * NT + nt][kb4 + kq];
                acc[i][0] = fmaf(xv.x, w0.x, acc[i][0]);
                acc[i][1] = fmaf(xv.x, w0.y, acc[i][1]);
                acc[i][2] = fmaf(xv.x, w0.z, acc[i][2]);
                acc[i][3] = fmaf(xv.x, w0.w, acc[i][3]);
                acc[i][0] = fmaf(xv.y, w1.x, acc[i][0]);
                acc[i][1] = fmaf(xv.y, w1.y, acc[i][1]);
                acc[i][2] = fmaf(xv.y, w1.z, acc[i][2]);
                acc[i][3] = fmaf(xv.y, w1.w, acc[i][3]);
                acc[i][0] = fmaf(xv.z, w2.x, acc[i][0]);
                acc[i][1] = fmaf(xv.z, w2.y, acc[i][1]);
                acc[i][2] = fmaf(xv.z, w2.z, acc[i][2]);
                acc[i][3] = fmaf(xv.z, w2.w, acc[i][3]);
                acc[i][0] = fmaf(xv.w, w3.x, acc[i][0]);
                acc[i][1] = fmaf(xv.w, w3.y, acc[i][1]);
                acc[i][2] = fmaf(xv.w, w3.z, acc[i][2]);
                acc[i][3] = fmaf(xv.w, w3.w, acc[i][3]);
            }
        }
    }

    // epilogue: bf16 H write + alpha partial dots via LDS float atomics (fp32)
    float a0 = asrc[4*ct], a1 = asrc[4*ct+1], a2 = asrc[4*ct+2], a3 = asrc[4*ct+3];
    float d0 = adst[4*ct], d1 = adst[4*ct+1], d2 = adst[4*ct+2], d3 = adst[4*ct+3];
    #pragma unroll
    for (int i = 0; i < NP; ++i) {
        int nl = i * NT + nt;
        int n  = nb + nl;
        float pa = acc[i][0]*a0 + acc[i][1]*a1 + acc[i][2]*a2 + acc[i][3]*a3;
        float pd = acc[i][0]*d0 + acc[i][1]*d1 + acc[i][2]*d2 + acc[i][3]*d3;
        atomicAdd(&red[2 * nl    ], pa);
        atomicAdd(&red[2 * nl + 1], pd);
        if (n < N_NODES) {
            ushort4 o;
            o.x = f2bf(acc[i][0]); o.y = f2bf(acc[i][1]);
            o.z = f2bf(acc[i][2]); o.w = f2bf(acc[i][3]);
            reinterpret_cast<ushort4*>(Hb)[(size_t)n * CQ + ct] = o;
        }
    }
    __syncthreads();
    for (int idx = t; idx < NPB; idx += BLK) {
        int n = nb + idx;
        if (n < N_NODES) { as[n] = red[2 * idx]; ad[n] = red[2 * idx + 1]; }
    }
}

// ---------------- fused segment softmax + aggregation, one wave per dst ----------------
// bf16 h gather. Per 64-edge chunk: all lanes compute w=exp(leaky(as+ad)-mx) once,
// then gather distributes src/w by shfl. VEC channels per lane; SLOTS edges in parallel.
// EPI 0: out = relu(agg + bias); EPI 1: out = log_softmax(agg + bias)

template<int C, int VEC, int UN, int EPI>
__global__ __launch_bounds__(256)
void k_node_agg(const int* __restrict__ rp, const int* __restrict__ csr_src,
                const float* __restrict__ as, const float* __restrict__ ad,
                const void* __restrict__ hv, const float* __restrict__ bias,
                float* __restrict__ outp) {
    constexpr int CL    = C / VEC;      // lanes per edge row (12 or 10)
    constexpr int SLOTS = 64 / CL;      // edges per gather step (5 or 6)
    int n = blockIdx.x * 4 + (threadIdx.x >> 6);
    int lane = threadIdx.x & 63;
    int beg = rp[n], end = rp[n + 1];
    float adn = ad[n];

    // per-lane first-chunk edge + segment max
    int j0 = beg + lane;
    int sj = (j0 < end) ? csr_src[j0] : 0;
    float v = as[sj] + adn; v = (v >= 0.f) ? v : NEG_SLOPE * v;
    float mx = (j0 < end) ? v : -INFINITY;
    for (int j = j0 + 64; j < end; j += 64) {
        int s2 = csr_src[j];
        float v2 = as[s2] + adn; v2 = (v2 >= 0.f) ? v2 : NEG_SLOPE * v2;
        mx = fmaxf(mx, v2);
    }
    #pragma unroll
    for (int off = 32; off; off >>= 1) mx = fmaxf(mx, __shfl_xor(mx, off));

    const int slot = lane / CL;
    const int c    = lane - slot * CL;
    const bool slotok = slot < SLOTS;

    float acc[VEC];
    #pragma unroll
    for (int k = 0; k < VEC; ++k) acc[k] = 0.f;
    float s_lane = 0.f;

    for (int cb = beg; cb < end; cb += 64) {
        int cnt = min(64, end - cb);
        float w;
        if (cb == beg) {
            w = (j0 < end) ? __expf(v - mx) : 0.f;
        } else {
            int j = cb + lane;
            int s2 = (j < end) ? csr_src[j] : 0;
            float v2 = as[s2] + adn; v2 = (v2 >= 0.f) ? v2 : NEG_SLOPE * v2;
            w = (j < end) ? __expf(v2 - mx) : 0.f;
            sj = s2;
        }
        s_lane += w;

        for (int base = 0; base < cnt; base += SLOTS * UN) {
            #pragma unroll
            for (int u = 0; u < UN; ++u) {
                int jj = base + u * SLOTS + slot;
                bool act = slotok && (jj < cnt);
                int jjc = act ? jj : 0;
                int   srcu = __shfl(sj, jjc);
                float wu   = __shfl(w,  jjc);
                if (act) {
                    if constexpr (VEC == 8) {
                        int4 g = reinterpret_cast<const int4*>(hv)[(size_t)srcu * CL + c];
                        acc[0] = fmaf(wu, bfu_lo(g.x), acc[0]);
                        acc[1] = fmaf(wu, bfu_hi(g.x), acc[1]);
                        acc[2] = fmaf(wu, bfu_lo(g.y), acc[2]);
                        acc[3] = fmaf(wu, bfu_hi(g.y), acc[3]);
                        acc[4] = fmaf(wu, bfu_lo(g.z), acc[4]);
                        acc[5] = fmaf(wu, bfu_hi(g.z), acc[5]);
                        acc[6] = fmaf(wu, bfu_lo(g.w), acc[6]);
                        acc[7] = fmaf(wu, bfu_hi(g.w), acc[7]);
                    } else {
                        uint2 g = reinterpret_cast<const uint2*>(hv)[(size_t)srcu * CL + c];
                        acc[0] = fmaf(wu, bfu_lo(g.x), acc[0]);
                        acc[1] = fmaf(wu, bfu_hi(g.x), acc[1]);
                        acc[2] = fmaf(wu, bfu_lo(g.y), acc[2]);
                        acc[3] = fmaf(wu, bfu_hi(g.y), acc[3]);
                    }
                }
            }
        }
    }

    // fold slot accumulators into lanes [0, CL): gather from immutable acc
    float tot[VEC];
    #pragma unroll
    for (int k = 0; k < VEC; ++k) tot[k] = acc[k];
    #pragma unroll
    for (int s = 1; s < SLOTS; ++s) {
        int sl = (lane + CL * s) & 63;      // for lane<CL never wraps
        #pragma unroll
        for (int k = 0; k < VEC; ++k) tot[k] += __shfl(acc[k], sl);
    }
    float ssum = s_lane;
    #pragma unroll
    for (int off = 32; off; off >>= 1) ssum += __shfl_xor(ssum, off);
    float inv = 1.f / ssum;

    if (EPI == 0) {
        if (lane < CL) {
            const float* b = bias + lane * VEC;
            float4* o = reinterpret_cast<float4*>(outp) + (size_t)n * (C / 4) + lane * (VEC / 4);
            #pragma unroll
            for (int q = 0; q < VEC / 4; ++q) {
                float4 ov;
                ov.x = fmaxf(fmaf(tot[4*q+0], inv, b[4*q+0]), 0.f);
                ov.y = fmaxf(fmaf(tot[4*q+1], inv, b[4*q+1]), 0.f);
                ov.z = fmaxf(fmaf(tot[4*q+2], inv, b[4*q+2]), 0.f);
                ov.w = fmaxf(fmaf(tot[4*q+3], inv, b[4*q+3]), 0.f);
                o[q] = ov;
            }
        }
    } else {
        bool actw = lane < CL;
        float v0 = -INFINITY, v1 = -INFINITY, v2 = -INFINITY, v3 = -INFINITY;
        if (actw) {
            const float* b = bias + lane * 4;
            v0 = fmaf(tot[0], inv, b[0]); v1 = fmaf(tot[1], inv, b[1]);
            v2 = fmaf(tot[2], inv, b[2]); v3 = fmaf(tot[3], inv, b[3]);
        }
        float vm = fmaxf(fmaxf(v0, v1), fmaxf(v2, v3));
        #pragma unroll
        for (int off = 32; off; off >>= 1) vm = fmaxf(vm, __shfl_xor(vm, off));
        float es = actw ? (__expf(v0 - vm) + __expf(v1 - vm) +
                           __expf(v2 - vm) + __expf(v3 - vm)) : 0.f;
        #pragma unroll
        for (int off = 32; off; off >>= 1) es += __shfl_xor(es, off);
        float lse = vm + logf(es);
        if (actw) {
            float4 ov = make_float4(v0 - lse, v1 - lse, v2 - lse, v3 - lse);
            reinterpret_cast<float4*>(outp)[(size_t)n * (C / 4) + lane] = ov;
        }
    }
}

// ---------------- launch ----------------

extern "C" void kernel_launch(void* const* d_in, const int* in_sizes, int n_in,
                              void* d_out, int out_size, void* d_ws, size_t ws_size,
                              hipStream_t stream) {
    const float* x      = (const float*)d_in[0];
    const int*   ei     = (const int*)d_in[1];
    const float* W1     = (const float*)d_in[3];
    const float* a_src1 = (const float*)d_in[4];
    const float* a_dst1 = (const float*)d_in[5];
    const float* b1     = (const float*)d_in[6];
    const float* W2     = (const float*)d_in[7];
    const float* a_src2 = (const float*)d_in[8];
    const float* a_dst2 = (const float*)d_in[9];
    const float* b2     = (const float*)d_in[10];
    float* out = (float*)d_out;

    float* wsf = (float*)d_ws;
    size_t off = 0;
    float* x2  = wsf + off; off += (size_t)N_NODES * C_HID;   // fp32 layer-2 input
    float* as1 = wsf + off; off += N_NODES;
    float* ad1 = wsf + off; off += N_NODES;
    float* as2 = wsf + off; off += N_NODES;
    float* ad2 = wsf + off; off += N_NODES;
    unsigned short* h1 = (unsigned short*)(wsf + off); off += (size_t)N_NODES * C_HID / 2;
    unsigned short* h2 = (unsigned short*)(wsf + off); off += (size_t)N_NODES * C_OUT / 2;
    int* wsi     = (int*)(wsf + off);
    size_t ioff  = 0;
    int* deg     = wsi + ioff; ioff += N_NODES;
    int* row_ptr = wsi + ioff; ioff += N_NODES + 1;
    int* cursor  = wsi + ioff; ioff += N_NODES;
    int* csr_src = wsi + ioff; ioff += N_ETOT;
    int* bsum    = wsi + ioff; ioff += NSB;
    int* boff    = wsi + ioff; ioff += NSB;

    // CSR build (shared by both layers), dst-partitioned for XCD locality
    k_initdeg<<<(N_NODES + 255) / 256, 256, 0, stream>>>(deg);
    k_hist<<<2048, 256, 0, stream>>>(ei, deg);
    k_scan1<<<NSB, 1024, 0, stream>>>(deg, row_ptr, bsum);
    k_scan2<<<1, 64, 0, stream>>>(bsum, boff, row_ptr);
    k_scan3<<<(N_NODES + 1023) / 1024, 1024, 0, stream>>>(row_ptr, boff, cursor);
    k_scatter<<<2048, 256, 0, stream>>>(ei, cursor, csr_src);

    // layer 1: 64-node blocks, 192 thr (24 col-thr x 8 node-thr x NP=8)
    k_gemm<C_IN, C_HID, 32, 24, 8, 8><<<(N_NODES + 63) / 64, 192, 0, stream>>>(
        x, W1, a_src1, a_dst1, h1, as1, ad1);
    k_node_agg<C_HID, 8, 2, 0><<<N_NODES / 4, 256, 0, stream>>>(
        row_ptr, csr_src, as1, ad1, h1, b1, x2);

    // layer 2: 128-node blocks, 320 thr (10 col-thr x 32 node-thr x NP=4), K staged once
    k_gemm<C_HID, C_OUT, 96, 10, 32, 4><<<(N_NODES + 127) / 128, 320, 0, stream>>>(
        x2, W2, a_src2, a_dst2, h2, as2, ad2);
    k_node_agg<C_OUT, 4, 2, 1><<<N_NODES / 4, 256, 0, stream>>>(
        row_ptr, csr_src, as2, ad2, h2, b2, out);
}

// Round 12
// 315.511 us; speedup vs baseline: 1.0044x; 1.0044x over previous
//
#include <hip/hip_runtime.h>
#include <math.h>

#define N_NODES 50000
#define N_EDGES 800000
#define N_ETOT  850000          // + self loops
#define C_IN    128
#define C_HID   96
#define C_OUT   40
#define NEG_SLOPE 0.2f
#define NSB ((N_NODES + 1023) / 1024)   // 49 scan blocks
#define NPART 8
#define PART_SZ ((N_NODES + NPART - 1) / NPART)   // 6250

// ---------------- bf16 helpers ----------------
__device__ __forceinline__ unsigned short f2bf(float f) {
    unsigned u = __float_as_uint(f);
    u = u + 0x7fffu + ((u >> 16) & 1u);     // round-to-nearest-even
    return (unsigned short)(u >> 16);
}
__device__ __forceinline__ float bfu_lo(unsigned g) { return __uint_as_float(g << 16); }
__device__ __forceinline__ float bfu_hi(unsigned g) { return __uint_as_float(g & 0xffff0000u); }

// ---------------- CSR build ----------------

__global__ void k_initdeg(int* __restrict__ deg) {
    int i = blockIdx.x * blockDim.x + threadIdx.x;
    if (i < N_NODES) deg[i] = 1;            // self loop
}

// dst-partitioned histogram: blocks with bid%NPART==p count only dst in partition p
__global__ void k_hist(const int* __restrict__ ei, int* __restrict__ deg) {
    int p  = blockIdx.x & (NPART - 1);
    int qb = blockIdx.x / NPART;
    int nq = gridDim.x / NPART;
    int lo = p * PART_SZ, hi = min(N_NODES, lo + PART_SZ);
    int stride = nq * blockDim.x;
    for (int i = qb * blockDim.x + threadIdx.x; i < N_EDGES; i += stride) {
        int d = ei[N_EDGES + i];
        if (d >= lo && d < hi) atomicAdd(&deg[d], 1);
    }
}

// hierarchical exclusive scan: per-block scan -> scan of block sums -> add offsets
__global__ void k_scan1(const int* __restrict__ deg, int* __restrict__ rp,
                        int* __restrict__ bsum) {
    __shared__ int wsum[16];
    int t = threadIdx.x, lane = t & 63, w = t >> 6;
    int i = blockIdx.x * 1024 + t;
    int v = (i < N_NODES) ? deg[i] : 0;
    int inc = v;
    #pragma unroll
    for (int off = 1; off < 64; off <<= 1) {
        int u = __shfl_up(inc, off);
        if (lane >= off) inc += u;
    }
    if (lane == 63) wsum[w] = inc;
    __syncthreads();
    if (w == 0) {
        int sv = (lane < 16) ? wsum[lane] : 0;
        #pragma unroll
        for (int off = 1; off < 16; off <<= 1) {
            int u = __shfl_up(sv, off);
            if (lane >= off) sv += u;
        }
        if (lane < 16) wsum[lane] = sv;       // inclusive over waves
    }
    __syncthreads();
    int exc = ((w == 0) ? 0 : wsum[w - 1]) + inc - v;
    if (i < N_NODES) rp[i] = exc;
    if (t == 0) bsum[blockIdx.x] = wsum[15];
}

__global__ void k_scan2(const int* __restrict__ bsum, int* __restrict__ boff,
                        int* __restrict__ rp) {
    int lane = threadIdx.x;   // 64 threads
    int v = (lane < NSB) ? bsum[lane] : 0;
    int inc = v;
    #pragma unroll
    for (int off = 1; off < 64; off <<= 1) {
        int u = __shfl_up(inc, off);
        if (lane >= off) inc += u;
    }
    if (lane < NSB) boff[lane] = inc - v;
    if (lane == 63) rp[N_NODES] = inc;        // total == N_ETOT
}

__global__ void k_scan3(int* __restrict__ rp, const int* __restrict__ boff,
                        int* __restrict__ cursor) {
    int i = blockIdx.x * blockDim.x + threadIdx.x;
    if (i < N_NODES) {
        int v = rp[i] + boff[i >> 10];
        rp[i] = v; cursor[i] = v;
    }
}

// dst-partitioned scatter (XCD-local cursor atomics + csr_src lines)
__global__ void k_scatter(const int* __restrict__ ei, int* __restrict__ cursor,
                          int* __restrict__ csr_src) {
    int p  = blockIdx.x & (NPART - 1);
    int qb = blockIdx.x / NPART;
    int nq = gridDim.x / NPART;
    int lo = p * PART_SZ, hi = min(N_NODES, lo + PART_SZ);
    int stride = nq * blockDim.x;
    for (int i = qb * blockDim.x + threadIdx.x; i < N_ETOT; i += stride) {
        int src, dst;
        if (i < N_EDGES) { src = ei[i]; dst = ei[N_EDGES + i]; }   // coalesced reads
        else             { src = dst = i - N_EDGES; }
        if (dst >= lo && dst < hi) {
            int pos = atomicAdd(&cursor[dst], 1);
            csr_src[pos] = src;
        }
    }
}

// ---------------- GEMM + fused alpha dots, bf16 H output ----------------
// H[N, COUT](bf16) = X[N, CIN] @ W[CIN, COUT]; as[n]=H[n]·asrc; ad[n]=H[n]·adst (fp32)
// No X staging: each thread reads its NP rows' float4 direct from global (block's
// 32KB X slab is L1-resident; CT threads share each row). Only W chunk in LDS
// (13KB -> high occupancy). Node-interleaved mapping n = i*NT + nt.

template<int CIN, int COUT, int KH, int CT, int NT, int NP>
__global__ __launch_bounds__(CT * NT)
void k_gemm(const float* __restrict__ X, const float* __restrict__ W,
            const float* __restrict__ asrc, const float* __restrict__ adst,
            unsigned short* __restrict__ Hb, float* __restrict__ as, float* __restrict__ ad) {
    constexpr int NPB = NT * NP;
    constexpr int BLK = CT * NT;
    constexpr int KQ  = CIN / 4;        // f4 per x row
    constexpr int CQ  = COUT / 4;
    __shared__ float4 Ws4[KH][CQ + 1];
    __shared__ float red[NPB * 2];
    const int t  = threadIdx.x;
    const int nb = blockIdx.x * NPB;

    for (int idx = t; idx < NPB * 2; idx += BLK) red[idx] = 0.f;

    const int ct = t % CT, nt = t / CT;

    // per-thread row pointers (OOB rows clamp to last row; results discarded)
    const float4* xp[NP];
    #pragma unroll
    for (int i = 0; i < NP; ++i) {
        int n = nb + i * NT + nt;
        if (n >= N_NODES) n = N_NODES - 1;
        xp[i] = reinterpret_cast<const float4*>(X) + (size_t)n * KQ;
    }

    float acc[NP][4] = {};

    for (int kb = 0; kb < CIN; kb += KH) {
        __syncthreads();                    // Ws reusable
        for (int idx = t; idx < KH * CQ; idx += BLK) {
            int kk = idx / CQ, c4 = idx - kk * CQ;
            Ws4[kk][c4] = reinterpret_cast<const float4*>(W)[(size_t)(kb + kk) * CQ + c4];
        }
        __syncthreads();
        const int kb4 = kb / 4;
        #pragma unroll 2
        for (int kq = 0; kq < KH / 4; ++kq) {
            float4 w0 = Ws4[4 * kq + 0][ct];
            float4 w1 = Ws4[4 * kq + 1][ct];
            float4 w2 = Ws4[4 * kq + 2][ct];
            float4 w3 = Ws4[4 * kq + 3][ct];
            float4 xv[NP];
            #pragma unroll
            for (int i = 0; i < NP; ++i) xv[i] = xp[i][kb4 + kq];   // NP loads in flight
            #pragma unroll
            for (int i = 0; i < NP; ++i) {
                acc[i][0] = fmaf(xv[i].x, w0.x, acc[i][0]);
                acc[i][1] = fmaf(xv[i].x, w0.y, acc[i][1]);
                acc[i][2] = fmaf(xv[i].x, w0.z, acc[i][2]);
                acc[i][3] = fmaf(xv[i].x, w0.w, acc[i][3]);
                acc[i][0] = fmaf(xv[i].y, w1.x, acc[i][0]);
                acc[i][1] = fmaf(xv[i].y, w1.y, acc[i][1]);
                acc[i][2] = fmaf(xv[i].y, w1.z, acc[i][2]);
                acc[i][3] = fmaf(xv[i].y, w1.w, acc[i][3]);
                acc[i][0] = fmaf(xv[i].z, w2.x, acc[i][0]);
                acc[i][1] = fmaf(xv[i].z, w2.y, acc[i][1]);
                acc[i][2] = fmaf(xv[i].z, w2.z, acc[i][2]);
                acc[i][3] = fmaf(xv[i].z, w2.w, acc[i][3]);
                acc[i][0] = fmaf(xv[i].w, w3.x, acc[i][0]);
                acc[i][1] = fmaf(xv[i].w, w3.y, acc[i][1]);
                acc[i][2] = fmaf(xv[i].w, w3.z, acc[i][2]);
                acc[i][3] = fmaf(xv[i].w, w3.w, acc[i][3]);
            }
        }
    }

    // epilogue: bf16 H write + alpha partial dots via LDS float atomics (fp32)
    float a0 = asrc[4*ct], a1 = asrc[4*ct+1], a2 = asrc[4*ct+2], a3 = asrc[4*ct+3];
    float d0 = adst[4*ct], d1 = adst[4*ct+1], d2 = adst[4*ct+2], d3 = adst[4*ct+3];
    #pragma unroll
    for (int i = 0; i < NP; ++i) {
        int nl = i * NT + nt;
        int n  = nb + nl;
        float pa = acc[i][0]*a0 + acc[i][1]*a1 + acc[i][2]*a2 + acc[i][3]*a3;
        float pd = acc[i][0]*d0 + acc[i][1]*d1 + acc[i][2]*d2 + acc[i][3]*d3;
        atomicAdd(&red[2 * nl    ], pa);
        atomicAdd(&red[2 * nl + 1], pd);
        if (n < N_NODES) {
            ushort4 o;
            o.x = f2bf(acc[i][0]); o.y = f2bf(acc[i][1]);
            o.z = f2bf(acc[i][2]); o.w = f2bf(acc[i][3]);
            reinterpret_cast<ushort4*>(Hb)[(size_t)n * CQ + ct] = o;
        }
    }
    __syncthreads();
    for (int idx = t; idx < NPB; idx += BLK) {
        int n = nb + idx;
        if (n < N_NODES) { as[n] = red[2 * idx]; ad[n] = red[2 * idx + 1]; }
    }
}

// ---------------- fused segment softmax + aggregation, one wave per dst ----------------
// bf16 h gather. Per 64-edge chunk: all lanes compute w=exp(leaky(as+ad)-mx) once,
// then gather distributes src/w by shfl. VEC channels per lane; SLOTS edges in parallel.
// EPI 0: out = relu(agg + bias); EPI 1: out = log_softmax(agg + bias)

template<int C, int VEC, int UN, int EPI>
__global__ __launch_bounds__(256)
void k_node_agg(const int* __restrict__ rp, const int* __restrict__ csr_src,
                const float* __restrict__ as, const float* __restrict__ ad,
                const void* __restrict__ hv, const float* __restrict__ bias,
                float* __restrict__ outp) {
    constexpr int CL    = C / VEC;      // lanes per edge row (12 or 10)
    constexpr int SLOTS = 64 / CL;      // edges per gather step (5 or 6)
    int n = blockIdx.x * 4 + (threadIdx.x >> 6);
    int lane = threadIdx.x & 63;
    int beg = rp[n], end = rp[n + 1];
    float adn = ad[n];

    // per-lane first-chunk edge + segment max
    int j0 = beg + lane;
    int sj = (j0 < end) ? csr_src[j0] : 0;
    float v = as[sj] + adn; v = (v >= 0.f) ? v : NEG_SLOPE * v;
    float mx = (j0 < end) ? v : -INFINITY;
    for (int j = j0 + 64; j < end; j += 64) {
        int s2 = csr_src[j];
        float v2 = as[s2] + adn; v2 = (v2 >= 0.f) ? v2 : NEG_SLOPE * v2;
        mx = fmaxf(mx, v2);
    }
    #pragma unroll
    for (int off = 32; off; off >>= 1) mx = fmaxf(mx, __shfl_xor(mx, off));

    const int slot = lane / CL;
    const int c    = lane - slot * CL;
    const bool slotok = slot < SLOTS;

    float acc[VEC];
    #pragma unroll
    for (int k = 0; k < VEC; ++k) acc[k] = 0.f;
    float s_lane = 0.f;

    for (int cb = beg; cb < end; cb += 64) {
        int cnt = min(64, end - cb);
        float w;
        if (cb == beg) {
            w = (j0 < end) ? __expf(v - mx) : 0.f;
        } else {
            int j = cb + lane;
            int s2 = (j < end) ? csr_src[j] : 0;
            float v2 = as[s2] + adn; v2 = (v2 >= 0.f) ? v2 : NEG_SLOPE * v2;
            w = (j < end) ? __expf(v2 - mx) : 0.f;
            sj = s2;
        }
        s_lane += w;

        for (int base = 0; base < cnt; base += SLOTS * UN) {
            #pragma unroll
            for (int u = 0; u < UN; ++u) {
                int jj = base + u * SLOTS + slot;
                bool act = slotok && (jj < cnt);
                int jjc = act ? jj : 0;
                int   srcu = __shfl(sj, jjc);
                float wu   = __shfl(w,  jjc);
                if (act) {
                    if constexpr (VEC == 8) {
                        int4 g = reinterpret_cast<const int4*>(hv)[(size_t)srcu * CL + c];
                        acc[0] = fmaf(wu, bfu_lo(g.x), acc[0]);
                        acc[1] = fmaf(wu, bfu_hi(g.x), acc[1]);
                        acc[2] = fmaf(wu, bfu_lo(g.y), acc[2]);
                        acc[3] = fmaf(wu, bfu_hi(g.y), acc[3]);
                        acc[4] = fmaf(wu, bfu_lo(g.z), acc[4]);
                        acc[5] = fmaf(wu, bfu_hi(g.z), acc[5]);
                        acc[6] = fmaf(wu, bfu_lo(g.w), acc[6]);
                        acc[7] = fmaf(wu, bfu_hi(g.w), acc[7]);
                    } else {
                        uint2 g = reinterpret_cast<const uint2*>(hv)[(size_t)srcu * CL + c];
                        acc[0] = fmaf(wu, bfu_lo(g.x), acc[0]);
                        acc[1] = fmaf(wu, bfu_hi(g.x), acc[1]);
                        acc[2] = fmaf(wu, bfu_lo(g.y), acc[2]);
                        acc[3] = fmaf(wu, bfu_hi(g.y), acc[3]);
                    }
                }
            }
        }
    }

    // fold slot accumulators into lanes [0, CL): gather from immutable acc
    float tot[VEC];
    #pragma unroll
    for (int k = 0; k < VEC; ++k) tot[k] = acc[k];
    #pragma unroll
    for (int s = 1; s < SLOTS; ++s) {
        int sl = (lane + CL * s) & 63;      // for lane<CL never wraps
        #pragma unroll
        for (int k = 0; k < VEC; ++k) tot[k] += __shfl(acc[k], sl);
    }
    float ssum = s_lane;
    #pragma unroll
    for (int off = 32; off; off >>= 1) ssum += __shfl_xor(ssum, off);
    float inv = 1.f / ssum;

    if (EPI == 0) {
        if (lane < CL) {
            const float* b = bias + lane * VEC;
            float4* o = reinterpret_cast<float4*>(outp) + (size_t)n * (C / 4) + lane * (VEC / 4);
            #pragma unroll
            for (int q = 0; q < VEC / 4; ++q) {
                float4 ov;
                ov.x = fmaxf(fmaf(tot[4*q+0], inv, b[4*q+0]), 0.f);
                ov.y = fmaxf(fmaf(tot[4*q+1], inv, b[4*q+1]), 0.f);
                ov.z = fmaxf(fmaf(tot[4*q+2], inv, b[4*q+2]), 0.f);
                ov.w = fmaxf(fmaf(tot[4*q+3], inv, b[4*q+3]), 0.f);
                o[q] = ov;
            }
        }
    } else {
        bool actw = lane < CL;
        float v0 = -INFINITY, v1 = -INFINITY, v2 = -INFINITY, v3 = -INFINITY;
        if (actw) {
            const float* b = bias + lane * 4;
            v0 = fmaf(tot[0], inv, b[0]); v1 = fmaf(tot[1], inv, b[1]);
            v2 = fmaf(tot[2], inv, b[2]); v3 = fmaf(tot[3], inv, b[3]);
        }
        float vm = fmaxf(fmaxf(v0, v1), fmaxf(v2, v3));
        #pragma unroll
        for (int off = 32; off; off >>= 1) vm = fmaxf(vm, __shfl_xor(vm, off));
        float es = actw ? (__expf(v0 - vm) + __expf(v1 - vm) +
                           __expf(v2 - vm) + __expf(v3 - vm)) : 0.f;
        #pragma unroll
        for (int off = 32; off; off >>= 1) es += __shfl_xor(es, off);
        float lse = vm + logf(es);
        if (actw) {
            float4 ov = make_float4(v0 - lse, v1 - lse, v2 - lse, v3 - lse);
            reinterpret_cast<float4*>(outp)[(size_t)n * (C / 4) + lane] = ov;
        }
    }
}

// ---------------- launch ----------------

extern "C" void kernel_launch(void* const* d_in, const int* in_sizes, int n_in,
                              void* d_out, int out_size, void* d_ws, size_t ws_size,
                              hipStream_t stream) {
    const float* x      = (const float*)d_in[0];
    const int*   ei     = (const int*)d_in[1];
    const float* W1     = (const float*)d_in[3];
    const float* a_src1 = (const float*)d_in[4];
    const float* a_dst1 = (const float*)d_in[5];
    const float* b1     = (const float*)d_in[6];
    const float* W2     = (const float*)d_in[7];
    const float* a_src2 = (const float*)d_in[8];
    const float* a_dst2 = (const float*)d_in[9];
    const float* b2     = (const float*)d_in[10];
    float* out = (float*)d_out;

    float* wsf = (float*)d_ws;
    size_t off = 0;
    float* x2  = wsf + off; off += (size_t)N_NODES * C_HID;   // fp32 layer-2 input
    float* as1 = wsf + off; off += N_NODES;
    float* ad1 = wsf + off; off += N_NODES;
    float* as2 = wsf + off; off += N_NODES;
    float* ad2 = wsf + off; off += N_NODES;
    unsigned short* h1 = (unsigned short*)(wsf + off); off += (size_t)N_NODES * C_HID / 2;
    unsigned short* h2 = (unsigned short*)(wsf + off); off += (size_t)N_NODES * C_OUT / 2;
    int* wsi     = (int*)(wsf + off);
    size_t ioff  = 0;
    int* deg     = wsi + ioff; ioff += N_NODES;
    int* row_ptr = wsi + ioff; ioff += N_NODES + 1;
    int* cursor  = wsi + ioff; ioff += N_NODES;
    int* csr_src = wsi + ioff; ioff += N_ETOT;
    int* bsum    = wsi + ioff; ioff += NSB;
    int* boff    = wsi + ioff; ioff += NSB;

    // CSR build (shared by both layers), dst-partitioned for XCD locality
    k_initdeg<<<(N_NODES + 255) / 256, 256, 0, stream>>>(deg);
    k_hist<<<2048, 256, 0, stream>>>(ei, deg);
    k_scan1<<<NSB, 1024, 0, stream>>>(deg, row_ptr, bsum);
    k_scan2<<<1, 64, 0, stream>>>(bsum, boff, row_ptr);
    k_scan3<<<(N_NODES + 1023) / 1024, 1024, 0, stream>>>(row_ptr, boff, cursor);
    k_scatter<<<2048, 256, 0, stream>>>(ei, cursor, csr_src);

    // layer 1: 64-node blocks, 192 thr (24 col-thr x 8 node-thr x NP=8), W-only LDS
    k_gemm<C_IN, C_HID, 32, 24, 8, 8><<<(N_NODES + 63) / 64, 192, 0, stream>>>(
        x, W1, a_src1, a_dst1, h1, as1, ad1);
    k_node_agg<C_HID, 8, 2, 0><<<N_NODES / 4, 256, 0, stream>>>(
        row_ptr, csr_src, as1, ad1, h1, b1, x2);

    // layer 2: 128-node blocks, 320 thr (10 col-thr x 32 node-thr x NP=4), K staged once
    k_gemm<C_HID, C_OUT, 96, 10, 32, 4><<<(N_NODES + 127) / 128, 320, 0, stream>>>(
        x2, W2, a_src2, a_dst2, h2, as2, ad2);
    k_node_agg<C_OUT, 4, 2, 1><<<N_NODES / 4, 256, 0, stream>>>(
        row_ptr, csr_src, as2, ad2, h2, b2, out);
}